// Round 5
// baseline (1256.314 us; speedup 1.0000x reference)
//
#include <hip/hip_runtime.h>
#include <math.h>

typedef __bf16 bf16;
typedef __bf16 bf16x8 __attribute__((ext_vector_type(8)));
typedef __bf16 bf16x4 __attribute__((ext_vector_type(4)));
typedef __bf16 bf16x2 __attribute__((ext_vector_type(2)));
typedef float f32x4 __attribute__((ext_vector_type(4)));

#define ROWS 16384   // B*T

// ---- direct global->LDS 16B DMA (gfx950). LDS dest = wave-uniform base + lane*16.
typedef __attribute__((address_space(3))) void* lds_vp;
typedef const __attribute__((address_space(1))) void* glb_vp;
__device__ __forceinline__ void gload16(const void* g, void* l) {
  __builtin_amdgcn_global_load_lds((glb_vp)g, (lds_vp)l, 16, 0, 0);
}

// ---------------- 0. cast f32 -> bf16 (weights) ----------------
__global__ __launch_bounds__(256) void cast_kernel(
    const float* __restrict__ src, bf16* __restrict__ dst, int n)
{
  int i = (blockIdx.x * 256 + threadIdx.x) * 8;
  if (i >= n) return;
  float4 a = *(const float4*)(src + i);
  float4 b = *(const float4*)(src + i + 4);
  bf16x8 o;
  o[0] = (bf16)a.x; o[1] = (bf16)a.y; o[2] = (bf16)a.z; o[3] = (bf16)a.w;
  o[4] = (bf16)b.x; o[5] = (bf16)b.y; o[6] = (bf16)b.z; o[7] = (bf16)b.w;
  *(bf16x8*)(dst + i) = o;
}

// ---------------- 1. x = frame_features + sinusoidal PE (f32 in, bf16 out) ----
__global__ __launch_bounds__(256) void pe_add_kernel(
    const float* __restrict__ ff, const int* __restrict__ idx, bf16* __restrict__ x)
{
  int p   = blockIdx.x * 256 + threadIdx.x;
  int row = p >> 9;
  int j   = p & 511;
  float pos = (float)idx[row];
  float d2  = (float)(2 * j) * (1.0f / 1024.0f);
  float dv  = expf(-9.210340371976184f * d2);
  float ang = pos * dv;
  float s, c;
  sincosf(ang, &s, &c);
  int base = row * 1024 + 2 * j;
  float2 f = *(const float2*)(ff + base);
  bf16x2 o;
  o[0] = (bf16)(f.x + s);
  o[1] = (bf16)(f.y + c);
  *(bf16x2*)(x + base) = o;
}

// ---------------- 2. GEMM: C[M,N] = A[M,K]*Bw[N,K]^T + bias (+resid)(gelu?) ----
// flatmm-style: A via double-buffered LDS DMA, B direct L2->regs (ping-pong).
// Block 256x128, 4 waves stacked on rows, each wave 64x128 (4x8 MFMA tiles).
// One barrier per BK=32 phase; DMA/B-loads issued post-barrier (drain-free).
// Requires M == 16384 (64 M-blocks), K % 64 == 0.
template<bool GELU, bool RES>
__global__ __launch_bounds__(256, 2) void gemm_bt(
    const bf16* __restrict__ A, const bf16* __restrict__ Bw,
    const float* __restrict__ bias, const bf16* __restrict__ resid,
    bf16* __restrict__ C, int M, int N, int K)
{
  __shared__ bf16 smem[16384];   // 32 KB: bufA0|bufA1; epilogue repack overlays
  bf16* bufA0 = smem;
  bf16* bufA1 = smem + 8192;

  const int tid = threadIdx.x;

  int lid = blockIdx.y * gridDim.x + blockIdx.x;
  int xcd = lid & 7;
  int j   = lid >> 3;
  const int bm = (xcd * 8 + (j & 7)) * 256;   // XCD owns contiguous M-stripe
  const int bn = (j >> 3) * 128;

  const int wave = tid >> 6;
  const int lane = tid & 63;
  const int wr   = wave * 64;          // wave row offset in 256-row tile
  const int ln   = lane & 15;
  const int q    = lane >> 4;

  // A staging: chunk c (0..3) covers rows [(c*64+wave*16), +16);
  // lane l -> row +(l>>2), XOR-swizzled k-granule ((l&3)^((l>>3)&3))*8.
  const int srow = lane >> 2;
  const int sgr  = ((lane & 3) ^ ((lane >> 3) & 3)) * 8;
  // frag-read slot for granule q of row r: q ^ ((r>>1)&3); r%32 dep only via ln.
  const int slot = (q ^ ((ln >> 1) & 3)) * 8;

  const bf16* gA = A + (size_t)(bm + wave * 16 + srow) * K + sgr;
  const bf16* pB = Bw + (size_t)(bn + ln) * K + q * 8;

  f32x4 acc[4][8];
#pragma unroll
  for (int tm = 0; tm < 4; tm++)
#pragma unroll
    for (int tn = 0; tn < 8; tn++) acc[tm][tn] = {0.f, 0.f, 0.f, 0.f};

  bf16x8 b0[8], b1[8];

#define DMAA(buf, kk)                                                         \
  {                                                                           \
    _Pragma("unroll") for (int c = 0; c < 4; c++)                             \
        gload16(gA + (size_t)(c * 64) * K + (kk),                             \
                &buf[(c * 64 + wave * 16) * 32]);                             \
  }
#define LOADB(dst, kk)                                                        \
  {                                                                           \
    _Pragma("unroll") for (int tn = 0; tn < 8; tn++)                          \
        dst[tn] = *(const bf16x8*)(pB + (size_t)(tn * 16) * K + (kk));        \
  }
#define COMPUTE(buf, bv)                                                      \
  {                                                                           \
    bf16x8 af[4];                                                             \
    _Pragma("unroll") for (int tm = 0; tm < 4; tm++)                          \
        af[tm] = *(const bf16x8*)(&buf[(wr + tm * 16 + ln) * 32 + slot]);     \
    _Pragma("unroll") for (int tm = 0; tm < 4; tm++)                          \
        _Pragma("unroll") for (int tn = 0; tn < 8; tn++)                      \
            acc[tm][tn] = __builtin_amdgcn_mfma_f32_16x16x32_bf16(            \
                af[tm], bv[tn], acc[tm][tn], 0, 0, 0);                        \
  }

  // preload tile 0
  DMAA(bufA0, 0);
  LOADB(b0, 0);

  for (int k0 = 0; k0 < K; k0 += 64) {
    // phase A: compute tile k0 from bufA0/b0; prefetch k0+32 -> bufA1/b1
    __syncthreads();            // drains bufA0 DMA (issued one phase ago)
    DMAA(bufA1, k0 + 32);       // k0+32 < K always (K%64==0)
    LOADB(b1, k0 + 32);
    COMPUTE(bufA0, b0);
    // phase B: compute tile k0+32 from bufA1/b1; prefetch k0+64 -> bufA0/b0
    __syncthreads();
    if (k0 + 64 < K) {
      DMAA(bufA0, k0 + 64);
      LOADB(b0, k0 + 64);
    }
    COMPUTE(bufA1, b1);
  }
#undef DMAA
#undef LOADB
#undef COMPUTE

  // ---- epilogue: 4 passes (one per tm). acc[tm][tn][i] is at
  // (row = bm + wr + tm*16 + q*4 + i, col = bn + tn*16 + ln).
  // Repack through LDS (64 rows x 128 cols, stride 132) for coalesced stores.
  float bv[8];
#pragma unroll
  for (int tn = 0; tn < 8; tn++) bv[tn] = bias[bn + tn * 16 + ln];

  const int s_  = tid >> 2;        // slab row 0..63 for readback
  const int cb  = (tid & 3) * 32;  // col base for readback
#pragma unroll
  for (int tm = 0; tm < 4; tm++) {
    __syncthreads();   // K-loop LDS reads / prior pass readback done
#pragma unroll
    for (int tn = 0; tn < 8; tn++)
#pragma unroll
      for (int i = 0; i < 4; i++)
        smem[(wave * 16 + q * 4 + i) * 132 + tn * 16 + ln] =
            (bf16)(acc[tm][tn][i] + bv[tn]);
    __syncthreads();
    int gR = bm + (s_ >> 4) * 64 + tm * 16 + (s_ & 15);
    size_t rowoff = (size_t)gR * N + bn + cb;
    bf16x8 v[4];
#pragma unroll
    for (int u = 0; u < 4; u++) v[u] = *(const bf16x8*)&smem[s_ * 132 + cb + u * 8];
    if (RES) {
#pragma unroll
      for (int u = 0; u < 4; u++) {
        bf16x8 r = *(const bf16x8*)(resid + rowoff + u * 8);
#pragma unroll
        for (int e = 0; e < 8; e++) v[u][e] = (bf16)((float)v[u][e] + (float)r[e]);
      }
    }
    if (GELU) {
#pragma unroll
      for (int u = 0; u < 4; u++)
#pragma unroll
        for (int e = 0; e < 8; e++) {
          float a = (float)v[u][e];
          v[u][e] = (bf16)(0.5f * a * (1.0f + erff(a * 0.70710678118654752f)));
        }
    }
#pragma unroll
    for (int u = 0; u < 4; u++) *(bf16x8*)(C + rowoff + u * 8) = v[u];
  }
}

// ---------------- 3. windowed attention: one block per (window, head) ----------
__global__ __launch_bounds__(256) void attn_kernel(
    const bf16* __restrict__ qkv, bf16* __restrict__ o)
{
  __shared__ float sq[16][132], sk[16][132], sv[16][132];
  __shared__ float ss[16][17];

  int wid = blockIdx.x;
  int h   = wid & 7;
  int win = wid >> 3;
  int tb  = win * 16;

  int t  = threadIdx.x;
  int r  = t >> 4;
  int c8 = (t & 15) * 8;

  const bf16* base = qkv + (size_t)(tb + r) * 3072 + c8;
  bf16x8 qv = *(const bf16x8*)(base + h * 128);
  bf16x8 kv = *(const bf16x8*)(base + 1024 + h * 128);
  bf16x8 vv = *(const bf16x8*)(base + 2048 + h * 128);
#pragma unroll
  for (int u = 0; u < 8; u++) {
    sq[r][c8 + u] = (float)qv[u];
    sk[r][c8 + u] = (float)kv[u];
    sv[r][c8 + u] = (float)vv[u];
  }
  __syncthreads();

  {
    int i = t >> 4, jj = t & 15;
    float s = 0.f;
#pragma unroll 8
    for (int d = 0; d < 128; d++) s += sq[i][d] * sk[jj][d];
    ss[i][jj] = s * 0.08838834764831845f;
  }
  __syncthreads();

  if (t < 16) {
    float m = -1e30f;
    for (int jj = 0; jj < 16; jj++) m = fmaxf(m, ss[t][jj]);
    float sum = 0.f;
    for (int jj = 0; jj < 16; jj++) { float e = expf(ss[t][jj] - m); ss[t][jj] = e; sum += e; }
    float inv = 1.0f / sum;
    for (int jj = 0; jj < 16; jj++) ss[t][jj] *= inv;
  }
  __syncthreads();

  {
    int i = t >> 4; int d0 = (t & 15) * 8;
    float acc[8] = {0, 0, 0, 0, 0, 0, 0, 0};
#pragma unroll
    for (int jj = 0; jj < 16; jj++) {
      float a = ss[i][jj];
#pragma unroll
      for (int u = 0; u < 8; u++) acc[u] += a * sv[jj][d0 + u];
    }
    bf16* op = o + (size_t)(tb + i) * 1024 + h * 128 + d0;
#pragma unroll
    for (int u = 0; u < 8; u++) op[u] = (bf16)acc[u];
  }
}

// ---------------- 4. LayerNorm (row = 1024, biased var), templated output ------
template<typename OUT_T>
__global__ __launch_bounds__(256) void ln_kernel(
    const bf16* __restrict__ x, const float* __restrict__ g,
    const float* __restrict__ b, OUT_T* __restrict__ y)
{
  __shared__ float red[8];
  int row = blockIdx.x;
  int t   = threadIdx.x;
  int lane = t & 63, wave = t >> 6;

  bf16x4 v4 = *(const bf16x4*)(x + (size_t)row * 1024 + t * 4);
  float v[4];
  float s = 0.f, sq = 0.f;
#pragma unroll
  for (int u = 0; u < 4; u++) {
    v[u] = (float)v4[u];
    s += v[u];
    sq += v[u] * v[u];
  }
  for (int off = 32; off > 0; off >>= 1) {
    s  += __shfl_down(s, off);
    sq += __shfl_down(sq, off);
  }
  if (lane == 0) { red[wave * 2] = s; red[wave * 2 + 1] = sq; }
  __syncthreads();
  float st = red[0] + red[2] + red[4] + red[6];
  float qt = red[1] + red[3] + red[5] + red[7];
  float mean = st * (1.0f / 1024.0f);
  float var  = qt * (1.0f / 1024.0f) - mean * mean;
  float inv  = rsqrtf(var + 1e-5f);
  int c = t * 4;
  OUT_T* yr = y + (size_t)row * 1024 + c;
#pragma unroll
  for (int u = 0; u < 4; u++)
    yr[u] = (OUT_T)((v[u] - mean) * inv * g[c + u] + b[c + u]);
}

// ---------------- launch ----------------
extern "C" void kernel_launch(void* const* d_in, const int* in_sizes, int n_in,
                              void* d_out, int out_size, void* d_ws, size_t ws_size,
                              hipStream_t stream) {
  const float* ff    = (const float*)d_in[0];
  const int*   idx   = (const int*)d_in[1];
  const float* w_qkv = (const float*)d_in[2];
  const float* b_qkv = (const float*)d_in[3];
  const float* w_out = (const float*)d_in[4];
  const float* b_out = (const float*)d_in[5];
  const float* w1    = (const float*)d_in[6];
  const float* b1    = (const float*)d_in[7];
  const float* w2    = (const float*)d_in[8];
  const float* b2    = (const float*)d_in[9];
  const float* g1    = (const float*)d_in[10];
  const float* be1   = (const float*)d_in[11];
  const float* g2    = (const float*)d_in[12];
  const float* be2   = (const float*)d_in[13];
  float* out = (float*)d_out;

  char* p = (char*)d_ws;
  bf16* x_bf = (bf16*)p;  p += (size_t)ROWS * 1024 * 2;   // 32MB
  bf16* big  = (bf16*)p;  p += (size_t)ROWS * 4096 * 2;   // 128MB: qkv|o, later gelu acts
  bf16* s_bf = (bf16*)p;  p += (size_t)ROWS * 1024 * 2;   // 32MB
  bf16* h_bf = (bf16*)p;  p += (size_t)ROWS * 1024 * 2;   // 32MB
  bf16* wqb  = (bf16*)p;  p += (size_t)3072 * 1024 * 2;
  bf16* wob  = (bf16*)p;  p += (size_t)1024 * 1024 * 2;
  bf16* w1b  = (bf16*)p;  p += (size_t)4096 * 1024 * 2;
  bf16* w2b  = (bf16*)p;  p += (size_t)1024 * 4096 * 2;
  bf16* o_bf = big + (size_t)ROWS * 3072;   // lives in big's tail during attention
  bf16* g_bf = big;                          // reuses big after attention done

  cast_kernel<<<3072 * 1024 / 8 / 256, 256, 0, stream>>>(w_qkv, wqb, 3072 * 1024);
  cast_kernel<<<1024 * 1024 / 8 / 256, 256, 0, stream>>>(w_out, wob, 1024 * 1024);
  cast_kernel<<<4096 * 1024 / 8 / 256, 256, 0, stream>>>(w1, w1b, 4096 * 1024);
  cast_kernel<<<1024 * 4096 / 8 / 256, 256, 0, stream>>>(w2, w2b, 1024 * 4096);

  pe_add_kernel<<<ROWS * 512 / 256, 256, 0, stream>>>(ff, idx, x_bf);
  gemm_bt<false, false><<<dim3(3072 / 128, 64), 256, 0, stream>>>(
      x_bf, wqb, b_qkv, nullptr, big, ROWS, 3072, 1024);
  attn_kernel<<<(ROWS / 16) * 8, 256, 0, stream>>>(big, o_bf);
  gemm_bt<false, true><<<dim3(1024 / 128, 64), 256, 0, stream>>>(
      o_bf, wob, b_out, x_bf, s_bf, ROWS, 1024, 1024);
  ln_kernel<bf16><<<ROWS, 256, 0, stream>>>(s_bf, g1, be1, h_bf);
  gemm_bt<true, false><<<dim3(4096 / 128, 64), 256, 0, stream>>>(
      h_bf, w1b, b1, nullptr, g_bf, ROWS, 4096, 1024);
  gemm_bt<false, true><<<dim3(1024 / 128, 64), 256, 0, stream>>>(
      g_bf, w2b, b2, h_bf, s_bf, ROWS, 1024, 4096);
  ln_kernel<float><<<ROWS, 256, 0, stream>>>(s_bf, g2, be2, out);
}

// Round 6
// 831.754 us; speedup vs baseline: 1.5104x; 1.5104x over previous
//
#include <hip/hip_runtime.h>
#include <math.h>

typedef __bf16 bf16;
typedef __bf16 bf16x8 __attribute__((ext_vector_type(8)));
typedef __bf16 bf16x4 __attribute__((ext_vector_type(4)));
typedef __bf16 bf16x2 __attribute__((ext_vector_type(2)));
typedef float f32x4 __attribute__((ext_vector_type(4)));

#define ROWS 16384   // B*T

// ---------------- 0. cast f32 -> bf16 (weights) ----------------
__global__ __launch_bounds__(256) void cast_kernel(
    const float* __restrict__ src, bf16* __restrict__ dst, int n)
{
  int i = (blockIdx.x * 256 + threadIdx.x) * 8;
  if (i >= n) return;
  float4 a = *(const float4*)(src + i);
  float4 b = *(const float4*)(src + i + 4);
  bf16x8 o;
  o[0] = (bf16)a.x; o[1] = (bf16)a.y; o[2] = (bf16)a.z; o[3] = (bf16)a.w;
  o[4] = (bf16)b.x; o[5] = (bf16)b.y; o[6] = (bf16)b.z; o[7] = (bf16)b.w;
  *(bf16x8*)(dst + i) = o;
}

// ---------------- 1. x = frame_features + sinusoidal PE (f32 in, bf16 out) ----
__global__ __launch_bounds__(256) void pe_add_kernel(
    const float* __restrict__ ff, const int* __restrict__ idx, bf16* __restrict__ x)
{
  int p   = blockIdx.x * 256 + threadIdx.x;
  int row = p >> 9;
  int j   = p & 511;
  float pos = (float)idx[row];
  float d2  = (float)(2 * j) * (1.0f / 1024.0f);
  float dv  = expf(-9.210340371976184f * d2);
  float ang = pos * dv;
  float s, c;
  sincosf(ang, &s, &c);
  int base = row * 1024 + 2 * j;
  float2 f = *(const float2*)(ff + base);
  bf16x2 o;
  o[0] = (bf16)(f.x + s);
  o[1] = (bf16)(f.y + c);
  *(bf16x2*)(x + base) = o;
}

// ---------------- 2. GEMM: C[M,N] = A[M,K]*Bw[N,K]^T + bias (+resid)(gelu?) ----
// Register-staged (round-2 core, best measured) + explicit 1-deep prefetch +
// xor-(row&3) LDS swizzle on unpadded stride-32 (bank-balanced writes+reads) +
// XCD->N-stripe swizzle (B panel fits per-XCD L2) + coalesced LDS epilogue.
// Requires: M%128==0, gridDim.x%8==0 or ==8*k with per=gx/8 (here 32/8/24/8),
// K%32==0.
template<bool GELU, bool RES>
__global__ __launch_bounds__(256, 2) void gemm_bt(
    const bf16* __restrict__ A, const bf16* __restrict__ Bw,
    const float* __restrict__ bias, const bf16* __restrict__ resid,
    bf16* __restrict__ C, int M, int N, int K)
{
  __shared__ bf16 smem[8192];   // 16 KB: sA|sB; epilogue repack overlays
  bf16* sA = smem;
  bf16* sB = smem + 4096;

  const int tid = threadIdx.x;

  // XCD swizzle: stripe s = lid&7 owns N-columns [s*per, (s+1)*per) blocks.
  int lid = blockIdx.y * gridDim.x + blockIdx.x;
  int per = gridDim.x >> 3;                 // N-blocks per XCD stripe
  int s   = lid & 7;
  int t_  = lid >> 3;
  const int bn = (s * per + (t_ % per)) * 128;
  const int bm = (t_ / per) * 128;

  const int wave = tid >> 6;
  const int lane = tid & 63;
  const int wr   = (wave >> 1) * 64;   // wave row offset in tile
  const int wc   = (wave & 1) * 64;    // wave col offset in tile
  const int ln   = lane & 15;
  const int q    = lane >> 4;

  // staging: thread t -> rows (t>>2) and (t>>2)+64; k-granule g=t&3 stored at
  // physical granule p = g ^ (row&3). Bank-balanced for b128 writes & reads.
  const int sr = tid >> 2;
  const int sg = tid & 3;
  const int p0 = (sg ^ (sr & 3)) * 8;        // same for row sr and sr+64
  // frag read: row = wr|wc + tm*16 + ln -> row&3 == ln&3
  const int slot = (q ^ (ln & 3)) * 8;

  f32x4 acc[4][4];
#pragma unroll
  for (int i = 0; i < 4; i++)
#pragma unroll
    for (int jj = 0; jj < 4; jj++) acc[i][jj] = {0.f, 0.f, 0.f, 0.f};

  const bf16* pa0 = A  + (size_t)(bm + sr)      * K + sg * 8;
  const bf16* pa1 = A  + (size_t)(bm + sr + 64) * K + sg * 8;
  const bf16* pb0 = Bw + (size_t)(bn + sr)      * K + sg * 8;
  const bf16* pb1 = Bw + (size_t)(bn + sr + 64) * K + sg * 8;

  // preload k0 = 0
  float4 a0 = *(const float4*)(pa0);
  float4 a1 = *(const float4*)(pa1);
  float4 b0 = *(const float4*)(pb0);
  float4 b1 = *(const float4*)(pb1);

  for (int k0 = 0; k0 < K; k0 += 32) {
    // prefetch next tile while current computes (1-deep pipeline)
    float4 na0, na1, nb0, nb1;
    if (k0 + 32 < K) {
      na0 = *(const float4*)(pa0 + k0 + 32);
      na1 = *(const float4*)(pa1 + k0 + 32);
      nb0 = *(const float4*)(pb0 + k0 + 32);
      nb1 = *(const float4*)(pb1 + k0 + 32);
    }
    __syncthreads();   // previous iter's LDS reads done
    *(float4*)(&sA[sr * 32 + p0])        = a0;
    *(float4*)(&sA[(sr + 64) * 32 + p0]) = a1;
    *(float4*)(&sB[sr * 32 + p0])        = b0;
    *(float4*)(&sB[(sr + 64) * 32 + p0]) = b1;
    __syncthreads();

    bf16x8 af[4], bfr[4];
#pragma unroll
    for (int t = 0; t < 4; t++) {
      af[t]  = *(const bf16x8*)(&sA[(wr + t * 16 + ln) * 32 + slot]);
      bfr[t] = *(const bf16x8*)(&sB[(wc + t * 16 + ln) * 32 + slot]);
    }
#pragma unroll
    for (int tm = 0; tm < 4; tm++)
#pragma unroll
      for (int tn = 0; tn < 4; tn++)
        acc[tm][tn] = __builtin_amdgcn_mfma_f32_16x16x32_bf16(
            af[tm], bfr[tn], acc[tm][tn], 0, 0, 0);

    a0 = na0; a1 = na1; b0 = nb0; b1 = nb1;
  }

  // ---- epilogue: 4 passes (one per tm). C/D layout col=lane&15, row=q*4+reg.
  // Repack through LDS (32 rows x 128 cols, stride 132), store 2x16B/thread.
  const int lr_w = (wave >> 1) * 16 + q * 4;       // LDS row base for writes
  const int lr_r = tid >> 3;                       // LDS row for reads (0..31)
  const int cb   = (tid & 7) * 16;                 // col base for reads
#pragma unroll
  for (int tm = 0; tm < 4; tm++) {
    __syncthreads();   // prior pass reads / K-loop LDS reads done
#pragma unroll
    for (int tn = 0; tn < 4; tn++) {
      int gn = bn + wc + tn * 16 + ln;
      float bv = bias[gn];
#pragma unroll
      for (int i = 0; i < 4; i++)
        smem[(lr_w + i) * 132 + wc + tn * 16 + ln] = (bf16)(acc[tm][tn][i] + bv);
    }
    __syncthreads();
    int gR = bm + (lr_r >> 4) * 64 + tm * 16 + (lr_r & 15);
    size_t rowoff = (size_t)gR * N + bn + cb;
    bf16x8 v0 = *(const bf16x8*)&smem[lr_r * 132 + cb];
    bf16x8 v1 = *(const bf16x8*)&smem[lr_r * 132 + cb + 8];
    if (RES) {
      bf16x8 r0 = *(const bf16x8*)(resid + rowoff);
      bf16x8 r1 = *(const bf16x8*)(resid + rowoff + 8);
#pragma unroll
      for (int u = 0; u < 8; u++) {
        v0[u] = (bf16)((float)v0[u] + (float)r0[u]);
        v1[u] = (bf16)((float)v1[u] + (float)r1[u]);
      }
    }
    if (GELU) {
#pragma unroll
      for (int u = 0; u < 8; u++) {
        float a = (float)v0[u], b = (float)v1[u];
        v0[u] = (bf16)(0.5f * a * (1.0f + erff(a * 0.70710678118654752f)));
        v1[u] = (bf16)(0.5f * b * (1.0f + erff(b * 0.70710678118654752f)));
      }
    }
    *(bf16x8*)(C + rowoff)     = v0;
    *(bf16x8*)(C + rowoff + 8) = v1;
  }
}

// ---------------- 3. windowed attention: one block per (window, head) ----------
__global__ __launch_bounds__(256) void attn_kernel(
    const bf16* __restrict__ qkv, bf16* __restrict__ o)
{
  __shared__ float sq[16][132], sk[16][132], sv[16][132];
  __shared__ float ss[16][17];

  int wid = blockIdx.x;
  int h   = wid & 7;
  int win = wid >> 3;
  int tb  = win * 16;

  int t  = threadIdx.x;
  int r  = t >> 4;
  int c8 = (t & 15) * 8;

  const bf16* base = qkv + (size_t)(tb + r) * 3072 + c8;
  bf16x8 qv = *(const bf16x8*)(base + h * 128);
  bf16x8 kv = *(const bf16x8*)(base + 1024 + h * 128);
  bf16x8 vv = *(const bf16x8*)(base + 2048 + h * 128);
#pragma unroll
  for (int u = 0; u < 8; u++) {
    sq[r][c8 + u] = (float)qv[u];
    sk[r][c8 + u] = (float)kv[u];
    sv[r][c8 + u] = (float)vv[u];
  }
  __syncthreads();

  {
    int i = t >> 4, jj = t & 15;
    float s = 0.f;
#pragma unroll 8
    for (int d = 0; d < 128; d++) s += sq[i][d] * sk[jj][d];
    ss[i][jj] = s * 0.08838834764831845f;
  }
  __syncthreads();

  if (t < 16) {
    float m = -1e30f;
    for (int jj = 0; jj < 16; jj++) m = fmaxf(m, ss[t][jj]);
    float sum = 0.f;
    for (int jj = 0; jj < 16; jj++) { float e = expf(ss[t][jj] - m); ss[t][jj] = e; sum += e; }
    float inv = 1.0f / sum;
    for (int jj = 0; jj < 16; jj++) ss[t][jj] *= inv;
  }
  __syncthreads();

  {
    int i = t >> 4; int d0 = (t & 15) * 8;
    float acc[8] = {0, 0, 0, 0, 0, 0, 0, 0};
#pragma unroll
    for (int jj = 0; jj < 16; jj++) {
      float a = ss[i][jj];
#pragma unroll
      for (int u = 0; u < 8; u++) acc[u] += a * sv[jj][d0 + u];
    }
    bf16* op = o + (size_t)(tb + i) * 1024 + h * 128 + d0;
#pragma unroll
    for (int u = 0; u < 8; u++) op[u] = (bf16)acc[u];
  }
}

// ---------------- 4. LayerNorm (row = 1024, biased var), templated output ------
template<typename OUT_T>
__global__ __launch_bounds__(256) void ln_kernel(
    const bf16* __restrict__ x, const float* __restrict__ g,
    const float* __restrict__ b, OUT_T* __restrict__ y)
{
  __shared__ float red[8];
  int row = blockIdx.x;
  int t   = threadIdx.x;
  int lane = t & 63, wave = t >> 6;

  bf16x4 v4 = *(const bf16x4*)(x + (size_t)row * 1024 + t * 4);
  float v[4];
  float s = 0.f, sq = 0.f;
#pragma unroll
  for (int u = 0; u < 4; u++) {
    v[u] = (float)v4[u];
    s += v[u];
    sq += v[u] * v[u];
  }
  for (int off = 32; off > 0; off >>= 1) {
    s  += __shfl_down(s, off);
    sq += __shfl_down(sq, off);
  }
  if (lane == 0) { red[wave * 2] = s; red[wave * 2 + 1] = sq; }
  __syncthreads();
  float st = red[0] + red[2] + red[4] + red[6];
  float qt = red[1] + red[3] + red[5] + red[7];
  float mean = st * (1.0f / 1024.0f);
  float var  = qt * (1.0f / 1024.0f) - mean * mean;
  float inv  = rsqrtf(var + 1e-5f);
  int c = t * 4;
  OUT_T* yr = y + (size_t)row * 1024 + c;
#pragma unroll
  for (int u = 0; u < 4; u++)
    yr[u] = (OUT_T)((v[u] - mean) * inv * g[c + u] + b[c + u]);
}

// ---------------- launch ----------------
extern "C" void kernel_launch(void* const* d_in, const int* in_sizes, int n_in,
                              void* d_out, int out_size, void* d_ws, size_t ws_size,
                              hipStream_t stream) {
  const float* ff    = (const float*)d_in[0];
  const int*   idx   = (const int*)d_in[1];
  const float* w_qkv = (const float*)d_in[2];
  const float* b_qkv = (const float*)d_in[3];
  const float* w_out = (const float*)d_in[4];
  const float* b_out = (const float*)d_in[5];
  const float* w1    = (const float*)d_in[6];
  const float* b1    = (const float*)d_in[7];
  const float* w2    = (const float*)d_in[8];
  const float* b2    = (const float*)d_in[9];
  const float* g1    = (const float*)d_in[10];
  const float* be1   = (const float*)d_in[11];
  const float* g2    = (const float*)d_in[12];
  const float* be2   = (const float*)d_in[13];
  float* out = (float*)d_out;

  char* p = (char*)d_ws;
  bf16* x_bf = (bf16*)p;  p += (size_t)ROWS * 1024 * 2;   // 32MB
  bf16* big  = (bf16*)p;  p += (size_t)ROWS * 4096 * 2;   // 128MB: qkv|o, later gelu acts
  bf16* s_bf = (bf16*)p;  p += (size_t)ROWS * 1024 * 2;   // 32MB
  bf16* h_bf = (bf16*)p;  p += (size_t)ROWS * 1024 * 2;   // 32MB
  bf16* wqb  = (bf16*)p;  p += (size_t)3072 * 1024 * 2;
  bf16* wob  = (bf16*)p;  p += (size_t)1024 * 1024 * 2;
  bf16* w1b  = (bf16*)p;  p += (size_t)4096 * 1024 * 2;
  bf16* w2b  = (bf16*)p;  p += (size_t)1024 * 4096 * 2;
  bf16* o_bf = big + (size_t)ROWS * 3072;   // lives in big's tail during attention
  bf16* g_bf = big;                          // reuses big after attention done

  cast_kernel<<<3072 * 1024 / 8 / 256, 256, 0, stream>>>(w_qkv, wqb, 3072 * 1024);
  cast_kernel<<<1024 * 1024 / 8 / 256, 256, 0, stream>>>(w_out, wob, 1024 * 1024);
  cast_kernel<<<4096 * 1024 / 8 / 256, 256, 0, stream>>>(w1, w1b, 4096 * 1024);
  cast_kernel<<<1024 * 4096 / 8 / 256, 256, 0, stream>>>(w2, w2b, 1024 * 4096);

  pe_add_kernel<<<ROWS * 512 / 256, 256, 0, stream>>>(ff, idx, x_bf);
  gemm_bt<false, false><<<dim3(3072 / 128, ROWS / 128), 256, 0, stream>>>(
      x_bf, wqb, b_qkv, nullptr, big, ROWS, 3072, 1024);
  attn_kernel<<<(ROWS / 16) * 8, 256, 0, stream>>>(big, o_bf);
  gemm_bt<false, true><<<dim3(1024 / 128, ROWS / 128), 256, 0, stream>>>(
      o_bf, wob, b_out, x_bf, s_bf, ROWS, 1024, 1024);
  ln_kernel<bf16><<<ROWS, 256, 0, stream>>>(s_bf, g1, be1, h_bf);
  gemm_bt<true, false><<<dim3(4096 / 128, ROWS / 128), 256, 0, stream>>>(
      h_bf, w1b, b1, nullptr, g_bf, ROWS, 4096, 1024);
  gemm_bt<false, true><<<dim3(1024 / 128, ROWS / 128), 256, 0, stream>>>(
      g_bf, w2b, b2, h_bf, s_bf, ROWS, 1024, 4096);
  ln_kernel<float><<<ROWS, 256, 0, stream>>>(s_bf, g2, be2, out);
}